// Round 2
// baseline (3081.341 us; speedup 1.0000x reference)
//
#include <hip/hip_runtime.h>
#include <stdint.h>

// Problem constants
#define C_ 10
#define Q_ 1000
#define R_ 1024
#define N_ 512
#define S_ 10000
#define CQ 10000
#define KP 10240   // K padded to multiple of 256 for GEMM tiling
#define SPLITK 8
#define GPN 1048576

// Workspace layout (bytes). Fits inside round-1 footprint (~58.8 MB, known-safe).
#define OFF_DT    0ULL           // bf16 Dt [1024][KP]            20,971,520
#define OFF_GP    20971520ULL    // f32 GP  [8][1024][1024]       33,554,432  (reused as XB panels p>=1)
#define OFF_SIG   54525952ULL    // f32 sigma/L [1024][1024]       4,194,304
#define OFF_MU    58720256ULL    // f32 mu-sums [10][1024]            40,960
#define OFF_E     58761216ULL    // f32 E [522]                        2,088
#define OFF_CLS   58763304ULL    // f32 cls accum (pad to 8)
#define OFF_AMAX  58763312ULL    // u64 amax [10]                         80
#define OFF_CNT   58763392ULL    // int cnt [16]                          64
#define ZERO_BYTES 43200ULL      // OFF_MU .. OFF_CNT+64

typedef __attribute__((ext_vector_type(8))) short bf16x8;
typedef __attribute__((ext_vector_type(4))) float f32x4;

#define AIDX(i, j) (((i) << 7) + (((j) + (i)) & 127))
#define XIDX(j, r) (((j) << 6) + (((r) + (j)) & 63))

// =========================================================================
// k_front: scores + epsmax + convert(self-prep), independent block ranges
// =========================================================================
__global__ __launch_bounds__(256) void k_front(
    const float* __restrict__ box, const int* __restrict__ labels,
    const float* __restrict__ idd, const float* __restrict__ Wp,
    const float* __restrict__ bp, const float* __restrict__ we,
    const float* __restrict__ eps, uint16_t* __restrict__ Dt,
    float* __restrict__ mu, float* __restrict__ E, float* cls_accum,
    unsigned long long* amax) {
  __shared__ const float* rowsrc[64];
  __shared__ int rcls[64];
  __shared__ float T[64][65];
  __shared__ int s_cnt[C_];
  __shared__ float svv[4];
  __shared__ int ssi[4];
  int b = blockIdx.x;
  int t = threadIdx.x;

  if (b < 1270) {
    // ---------------- epsmax: per-class argmax of ||eps||^2 ----------------
    int c = b / 127, chunk = b % 127;
    int lane = t & 63, w = t >> 6;
    const int per = 79;
    int s0 = chunk * per;
    int s1 = min(s0 + per, S_);
    float bv = -1.f; int bs = 0;
    for (int s = s0 + w; s < s1; s += 4) {
      const float4* p = (const float4*)(eps + ((size_t)c * S_ + s) * R_);
      float acc = 0.f;
#pragma unroll
      for (int m = 0; m < 4; m++) {
        float4 v = p[lane + 64 * m];
        acc += v.x * v.x + v.y * v.y + v.z * v.z + v.w * v.w;
      }
#pragma unroll
      for (int d = 32; d > 0; d >>= 1) acc += __shfl_xor(acc, d);
      if (acc > bv) { bv = acc; bs = s; }
    }
    if (lane == 0) { svv[w] = bv; ssi[w] = bs; }
    __syncthreads();
    if (t == 0) {
      float m = svv[0]; int mi = ssi[0];
      for (int i = 1; i < 4; i++) if (svv[i] > m) { m = svv[i]; mi = ssi[i]; }
      if (m >= 0.f) {
        unsigned long long pk = ((unsigned long long)__float_as_uint(m) << 32) | (unsigned)mi;
        atomicMax(amax + c, pk);
      }
    }
    return;
  }

  if (b < 1270 + 128) {
    // ---------------- scores: 4 rows per block, one wave per row ----------------
    int lane = t & 63, wv = t >> 6;
    int i = (b - 1270) * 4 + wv;
    float s[C_];
#pragma unroll
    for (int k = 0; k < C_; k++) s[k] = 0.f;
    const float* bi = box + (size_t)i * R_;
    for (int r = lane; r < R_; r += 64) {
      float x = bi[r];
#pragma unroll
      for (int k = 0; k < C_; k++) s[k] += x * Wp[k * R_ + r];
    }
#pragma unroll
    for (int k = 0; k < C_; k++) {
#pragma unroll
      for (int d = 32; d > 0; d >>= 1) s[k] += __shfl_xor(s[k], d);
    }
    if (lane == 0) {
      int lab = labels[i];
      float sc[C_]; float m = -1e30f;
#pragma unroll
      for (int k = 0; k < C_; k++) { sc[k] = s[k] + bp[k]; m = fmaxf(m, sc[k]); }
      float fsum = 0.f, esum = 0.f;
#pragma unroll
      for (int k = 0; k < C_; k++) {
        float x = sc[k];
        float tt = (k == lab) ? 1.f : 0.f;
        float p = 1.f / (1.f + expf(-x));
        float ce = fmaxf(x, 0.f) - x * tt + log1pf(expf(-fabsf(x)));
        float pt = p * tt + (1.f - p) * (1.f - tt);
        float at = 0.25f * tt + 0.75f * (1.f - tt);
        float om = 1.f - pt;
        fsum += at * ce * om * om;
        esum += expf(x - m) * fmaxf(we[k], 0.f);
      }
      atomicAdd(cls_accum, fsum);
      E[i] = m + logf(esum);
    }
    return;
  }

  // ---------------- convert (with per-block self-prep) ----------------
  int cb = b - 1398;
  int bk = cb % 160, br = cb / 160;
  int t0 = bk * 64, r0 = br * 64;
  if (t < C_) s_cnt[t] = 0;
  __syncthreads();
  for (int i = t; i < N_; i += 256) atomicAdd(&s_cnt[labels[i]], 1);
  __syncthreads();
  if (t < 64) {
    int row = t0 + t;
    const float* src = nullptr; int c = -1;
    if (row < CQ) {
      c = row / Q_;
      int q = row - c * Q_;
      int k = s_cnt[c];
      if (q < Q_ - k) src = idd + (size_t)(c * Q_ + q + k) * R_;
      else {
        int m = q - (Q_ - k);           // m-th occurrence of label c, in order
        int cnt2 = 0, gi2 = 0;
        for (int i2 = 0; i2 < N_; i2++) {
          if (labels[i2] == c) { if (cnt2 == m) { gi2 = i2; break; } cnt2++; }
        }
        src = box + (size_t)gi2 * R_;
      }
    }
    rowsrc[t] = src; rcls[t] = c;
  }
  __syncthreads();
  int rr = t & 63, k4 = t >> 6;
#pragma unroll
  for (int it = 0; it < 16; it++) {
    int kk = k4 + it * 4;
    const float* src = rowsrc[kk];
    T[kk][rr] = src ? src[r0 + rr] : 0.f;
  }
  __syncthreads();
  if (t < 64 && t0 < CQ) {
    int c0 = rcls[0];
    float s0 = 0.f, s1 = 0.f; int c1 = -1;
    for (int kk = 0; kk < 64; kk++) {
      int c = rcls[kk]; float v = T[kk][t];
      if (c == c0) s0 += v; else if (c >= 0) { c1 = c; s1 += v; }
    }
    atomicAdd(&mu[c0 * R_ + r0 + t], s0);
    if (c1 >= 0) atomicAdd(&mu[c1 * R_ + r0 + t], s1);
  }
  int kk2 = t & 63, r4 = t >> 6;
#pragma unroll
  for (int it = 0; it < 16; it++) {
    int rr2 = r4 + it * 4;
    float v = T[kk2][rr2];
    uint32_t u = __float_as_uint(v);
    uint32_t bb = (u + 0x7fffu + ((u >> 16) & 1u)) >> 16;   // RNE f32->bf16
    Dt[(size_t)(r0 + rr2) * KP + t0 + kk2] = (uint16_t)bb;
  }
}

// =========================================================================
// shared Cholesky pieces
// =========================================================================
// panel-blocked 128x128 factor over LDS arena a[16384] (AIDX swizzle)
__device__ void diag_factor(float* __restrict__ a) {
  int t = threadIdx.x;
  int lane = t & 63, wv = t >> 6;
  for (int panel = 0; panel < 8; panel++) {
    int j0 = panel * 16;
    if (wv == 0) {
      float pa0[16], pa1[16];
#pragma unroll
      for (int jj = 0; jj < 16; jj++) {
        pa0[jj] = a[AIDX(lane, j0 + jj)];
        pa1[jj] = a[AIDX(lane + 64, j0 + jj)];
      }
#pragma unroll
      for (int jj = 0; jj < 16; jj++) {
        int j = j0 + jj;
        float pv0 = __shfl(pa0[jj], j & 63);
        float pv1 = __shfl(pa1[jj], j & 63);
        float pv = (j < 64) ? pv0 : pv1;
        float rsq = rsqrtf(pv);
        rsq = rsq * (1.5f - 0.5f * pv * rsq * rsq);   // Newton refine
        pa0[jj] *= rsq;
        pa1[jj] *= rsq;
#pragma unroll
        for (int kk = jj + 1; kk < 16; kk++) {
          int k = j0 + kk;
          float av0 = __shfl(pa0[jj], k & 63);
          float av1 = __shfl(pa1[jj], k & 63);
          float akj = (k < 64) ? av0 : av1;
          pa0[kk] -= pa0[jj] * akj;
          pa1[kk] -= pa1[jj] * akj;
        }
      }
#pragma unroll
      for (int jj = 0; jj < 16; jj++) {
        a[AIDX(lane, j0 + jj)] = pa0[jj];
        a[AIDX(lane + 64, j0 + jj)] = pa1[jj];
      }
    }
    __syncthreads();
    int m0 = j0 + 16;
    int M = 128 - m0;
    if (M > 0) {
      int T4 = M >> 2;
      int ntiles = T4 * (T4 + 1) / 2;
      for (int tb = t; tb < ntiles; tb += 256) {
        int I = (int)((sqrtf(8.f * tb + 1.f) - 1.f) * 0.5f);
        while ((I + 1) * (I + 2) / 2 <= tb) I++;
        while (I * (I + 1) / 2 > tb) I--;
        int K = tb - I * (I + 1) / 2;
        int gi = m0 + I * 4, gk = m0 + K * 4;
        float acc[4][4] = {{0.f}};
#pragma unroll
        for (int u = 0; u < 16; u++) {
          int jj = (u + t) & 15;
          float ai[4], ak[4];
#pragma unroll
          for (int m = 0; m < 4; m++) ai[m] = a[AIDX(gi + m, j0 + jj)];
#pragma unroll
          for (int n = 0; n < 4; n++) ak[n] = a[AIDX(gk + n, j0 + jj)];
#pragma unroll
          for (int m = 0; m < 4; m++)
#pragma unroll
            for (int n = 0; n < 4; n++) acc[m][n] += ai[m] * ak[n];
        }
#pragma unroll
        for (int m = 0; m < 4; m++)
#pragma unroll
          for (int n = 0; n < 4; n++)
            a[AIDX(gi + m, gk + n)] -= acc[m][n];
      }
    }
    __syncthreads();
  }
}

// sigma correction applied at first touch (stage-0 / diag0 reads of raw G)
__device__ __forceinline__ float sig_corr(const float* __restrict__ GP,
                                          const float* __restrict__ mu,
                                          int i, int j) {
  size_t o = (size_t)i * 1024 + j;
  float g = 0.f;
#pragma unroll
  for (int s = 0; s < SPLITK; s++) g += GP[(size_t)s * GPN + o];
  float mm = 0.f;
#pragma unroll
  for (int c = 0; c < C_; c++) mm += mu[c * R_ + i] * mu[c * R_ + j];
  return g * 1e-4f - mm * 1e-7f + ((i == j) ? 1e-4f : 0.f);
}

// load diag block p (lower+diag; upper := 0), factor, store back to sig
__device__ void diag_tail(float* __restrict__ sig, const float* __restrict__ GP,
                          const float* __restrict__ mu, int p, int fromGP,
                          float* __restrict__ a) {
  int t = threadIdx.x;
  int base = p * 128;
  for (int idx = t; idx < 16384; idx += 256) {
    int i = idx >> 7, j = idx & 127;
    float v = 0.f;
    if (j <= i) {
      if (fromGP) v = sig_corr(GP, mu, base + i, base + j);
      else        v = sig[(size_t)(base + i) * 1024 + base + j];
    }
    a[AIDX(i, j)] = v;
  }
  __syncthreads();
  diag_factor(a);
  for (int idx = t; idx < 16384; idx += 256) {
    int i = idx >> 7, j = idx & 127;
    sig[(size_t)(base + i) * 1024 + base + j] = a[AIDX(i, j)];
  }
}

// solve 64-row panel X L00^T = A into XT (XIDX layout). L00 read from sig (L2).
__device__ void solve_panel(const float* __restrict__ sig, const float* __restrict__ GP,
                            const float* __restrict__ mu, int base, int grow,
                            int fromGP, float* __restrict__ XT, float rd0, float rd1) {
  int t = threadIdx.x;
  int r = t & 63, wv = t >> 6;
  for (int idx = t; idx < 8192; idx += 256) {
    int rr = idx >> 7, j = idx & 127;
    int gi = grow + rr, gj = base + j;
    float v;
    if (fromGP) v = sig_corr(GP, mu, gi, gj);
    else        v = sig[(size_t)gi * 1024 + gj];
    XT[XIDX(j, rr)] = v;
  }
  __syncthreads();
  const float* L00 = sig + (size_t)base * 1024 + base;   // row stride 1024
  for (int pb = 0; pb < 8; pb++) {
    int j0 = pb * 16;
    if (j0 > 0) {
      int c0 = j0 + wv * 4;
      const float* l0 = L00 + (size_t)c0 * 1024;
      float acc0 = 0.f, acc1 = 0.f, acc2 = 0.f, acc3 = 0.f;
      for (int k = 0; k < j0; k++) {
        float xk = XT[XIDX(k, r)];
        acc0 += xk * l0[k];
        acc1 += xk * l0[1024 + k];
        acc2 += xk * l0[2048 + k];
        acc3 += xk * l0[3072 + k];
      }
      XT[XIDX(c0 + 0, r)] -= acc0;
      XT[XIDX(c0 + 1, r)] -= acc1;
      XT[XIDX(c0 + 2, r)] -= acc2;
      XT[XIDX(c0 + 3, r)] -= acc3;
    }
    __syncthreads();
    if (wv == 0) {
#pragma unroll
      for (int jj = 0; jj < 16; jj++) {
        int j = j0 + jj;
        float rdj = (j < 64) ? __shfl(rd0, j) : __shfl(rd1, j - 64);
        float xj = XT[XIDX(j, r)] * rdj;
        XT[XIDX(j, r)] = xj;
#pragma unroll
        for (int kk = jj + 1; kk < 16; kk++) {
          int k2 = j0 + kk;
          XT[XIDX(k2, r)] -= xj * L00[(size_t)k2 * 1024 + j];
        }
      }
    }
    __syncthreads();
  }
}

// =========================================================================
// G = Dt * Dt^T via bf16 MFMA (split-K=8), last block factors diag0
// =========================================================================
__global__ __launch_bounds__(256) void k_gemm(const uint16_t* __restrict__ Dt,
                                              float* __restrict__ GP,
                                              const float* __restrict__ mu,
                                              float* __restrict__ sig,
                                              int* __restrict__ cnt) {
  __shared__ __align__(16) union SM {
    struct { uint16_t A[2][8192]; uint16_t B[2][8192]; } g;
    float a[16384];
  } sm;
  int bi = blockIdx.x, bj = blockIdx.y, bz = blockIdx.z;
  int t = threadIdx.x;
  int lane = t & 63, w = t >> 6;
  int i0 = bi * 128, j0 = bj * 128;
  int lane16 = lane & 15, quad = lane >> 4;
  int wm = w >> 1, wn = w & 1;
  int row = t >> 1, half = t & 1;
  int kz = bz * 1280;                      // 1280 bf16 per split, 20 steps of 64
  const uint16_t* ga = Dt + (size_t)(i0 + row) * KP + kz + half * 32;
  const uint16_t* gb = Dt + (size_t)(j0 + row) * KP + kz + half * 32;
  int swz[4];
#pragma unroll
  for (int u = 0; u < 4; u++) swz[u] = (((half << 2) | u) ^ (row & 7)) << 3;
  int x7 = lane16 & 7;

  f32x4 acc[4][4];
#pragma unroll
  for (int a = 0; a < 4; a++)
#pragma unroll
    for (int b = 0; b < 4; b++) acc[a][b] = (f32x4){0.f, 0.f, 0.f, 0.f};

  uint4 ra[4], rb[4];
#pragma unroll
  for (int u = 0; u < 4; u++) {
    ra[u] = *(const uint4*)(ga + u * 8);
    rb[u] = *(const uint4*)(gb + u * 8);
  }
#pragma unroll
  for (int u = 0; u < 4; u++) {
    *(uint4*)(sm.g.A[0] + row * 64 + swz[u]) = ra[u];
    *(uint4*)(sm.g.B[0] + row * 64 + swz[u]) = rb[u];
  }
  __syncthreads();

  for (int it = 0; it < 20; it++) {
    int cur = it & 1;
    bool more = (it + 1) < 20;
    if (more) {
      const uint16_t* pa = ga + (it + 1) * 64;
      const uint16_t* pb = gb + (it + 1) * 64;
#pragma unroll
      for (int u = 0; u < 4; u++) {
        ra[u] = *(const uint4*)(pa + u * 8);
        rb[u] = *(const uint4*)(pb + u * 8);
      }
    }
#pragma unroll
    for (int ch = 0; ch < 2; ch++) {
      bf16x8 af[4], bfr[4];
#pragma unroll
      for (int mi = 0; mi < 4; mi++) {
        int rr = wm * 64 + mi * 16 + lane16;
        int ck = ((ch << 2) | quad) ^ x7;
        af[mi] = *(const bf16x8*)(sm.g.A[cur] + rr * 64 + ck * 8);
      }
#pragma unroll
      for (int ni = 0; ni < 4; ni++) {
        int rr = wn * 64 + ni * 16 + lane16;
        int ck = ((ch << 2) | quad) ^ x7;
        bfr[ni] = *(const bf16x8*)(sm.g.B[cur] + rr * 64 + ck * 8);
      }
#pragma unroll
      for (int mi = 0; mi < 4; mi++)
#pragma unroll
        for (int ni = 0; ni < 4; ni++)
          acc[mi][ni] = __builtin_amdgcn_mfma_f32_16x16x32_bf16(af[mi], bfr[ni], acc[mi][ni], 0, 0, 0);
    }
    if (more) {
      int nxt = cur ^ 1;
#pragma unroll
      for (int u = 0; u < 4; u++) {
        *(uint4*)(sm.g.A[nxt] + row * 64 + swz[u]) = ra[u];
        *(uint4*)(sm.g.B[nxt] + row * 64 + swz[u]) = rb[u];
      }
    }
    __syncthreads();
  }
  float* gp = GP + (size_t)bz * GPN;
#pragma unroll
  for (int mi = 0; mi < 4; mi++)
#pragma unroll
    for (int ni = 0; ni < 4; ni++) {
      int col = j0 + wn * 64 + ni * 16 + lane16;
      int rowb = i0 + wm * 64 + mi * 16 + quad * 4;
#pragma unroll
      for (int r = 0; r < 4; r++)
        gp[(size_t)(rowb + r) * 1024 + col] = acc[mi][ni][r];
    }
  // ---- last block: sigma diag block 0 + factor (diag0) ----
  __syncthreads();
  if (t == 0) {
    __threadfence();
    int d = atomicAdd(&cnt[8], 1);
    sm.a[0] = (d == 511) ? 1.f : 0.f;
  }
  __syncthreads();
  bool last = (sm.a[0] != 0.f);
  __syncthreads();
  if (!last) return;
  __threadfence();
  diag_tail(sig, GP, mu, 0, 1, sm.a);
}

// =========================================================================
// fused trsm+syrk per stage p; last block factors diag p+1
// =========================================================================
__global__ __launch_bounds__(256) void k_tsyrk(float* __restrict__ sig,
                                               float* __restrict__ GP,
                                               const float* __restrict__ mu,
                                               int* __restrict__ cnt,
                                               int p, int nt) {
  __shared__ __align__(16) float arena[16384];   // XI | XK ; reused as diag arena
  float* XI = arena;
  float* XK = arena + 8192;
  int t = threadIdx.x;
  int base = p * 128;
  int bid = blockIdx.x;
  int I = 0;
  while ((I + 1) * (I + 2) / 2 <= bid) I++;
  int K = bid - I * (I + 1) / 2;
  int gi = base + 128 + I * 64, gk = base + 128 + K * 64;
  int r = t & 63, wv = t >> 6;
  float rd0 = 0.f, rd1 = 0.f;
  if (wv == 0) {
    rd0 = 1.0f / sig[(size_t)(base + r) * 1024 + base + r];
    rd1 = 1.0f / sig[(size_t)(base + 64 + r) * 1024 + base + 64 + r];
  }
  int fromGP = (p == 0);
  solve_panel(sig, GP, mu, base, gi, fromGP, XI, rd0, rd1);
  if (I != K) solve_panel(sig, GP, mu, base, gk, fromGP, XK, rd0, rd1);
  // diagonal tile publishes the L panel rows (race-free locations)
  if (I == K) {
    if (p == 0) {
      // sig's sub-diagonal columns [0,128) are unread during stage 0
      for (int idx = t; idx < 8192; idx += 256) {
        int rr = idx >> 7, j = idx & 127;
        sig[(size_t)(gi + rr) * 1024 + j] = XI[XIDX(j, rr)];
      }
    } else {
      // GP is dead after stage 0: park panel p there
      float* xb = GP + (size_t)(p - 1) * 114688;
      for (int idx = t; idx < 8192; idx += 256) {
        int rr = idx >> 7, j = idx & 127;
        xb[(size_t)(I * 64 + rr) * 128 + j] = XI[XIDX(j, rr)];
      }
    }
  }
  // ---- syrk: trailing update of this 64x64 tile ----
  const float* XKp = (I == K) ? XI : XK;
  int a4 = t >> 4, b4 = t & 15;
  float acc[4][4];
#pragma unroll
  for (int m = 0; m < 4; m++)
#pragma unroll
    for (int n = 0; n < 4; n++) acc[m][n] = 0.f;
  for (int j = 0; j < 128; j++) {
    float pa[4], pb[4];
#pragma unroll
    for (int m = 0; m < 4; m++) pa[m] = XI[XIDX(j, a4 * 4 + m)];
#pragma unroll
    for (int n = 0; n < 4; n++) pb[n] = XKp[XIDX(j, b4 * 4 + n)];
#pragma unroll
    for (int m = 0; m < 4; m++)
#pragma unroll
      for (int n = 0; n < 4; n++) acc[m][n] += pa[m] * pb[n];
  }
#pragma unroll
  for (int m = 0; m < 4; m++)
#pragma unroll
    for (int n = 0; n < 4; n++) {
      int ii = gi + a4 * 4 + m, jj = gk + b4 * 4 + n;
      size_t o = (size_t)ii * 1024 + jj;
      float v = fromGP ? sig_corr(GP, mu, ii, jj) : sig[o];
      sig[o] = v - acc[m][n];
    }
  // ---- last block: factor diag p+1 ----
  __syncthreads();
  if (t == 0) {
    __threadfence();
    int d = atomicAdd(&cnt[p], 1);
    arena[0] = (d == nt - 1) ? 1.f : 0.f;
  }
  __syncthreads();
  bool last = (arena[0] != 0.f);
  __syncthreads();
  if (!last) return;
  __threadfence();
  diag_tail(sig, GP, mu, p + 1, 0, arena);
}

// =========================================================================
// VOS per class (reads L from sig diag blocks + panel stores) ; last block: dist
// =========================================================================
__global__ __launch_bounds__(256) void k_vosdist(
    const float* __restrict__ eps, const float* __restrict__ sig,
    const float* __restrict__ XB, const float* __restrict__ mu,
    const float* __restrict__ Wp, const float* __restrict__ bp,
    const float* __restrict__ we, const unsigned long long* __restrict__ amax,
    float* __restrict__ E, const float* __restrict__ W1,
    const float* __restrict__ b1, const float* __restrict__ W2,
    const float* __restrict__ b2, const float* __restrict__ cls_accum,
    float* __restrict__ out, int* __restrict__ cnt) {
  __shared__ float es[1024];
  __shared__ float ys[1024];
  __shared__ float sv[16];
  __shared__ float darena[1540];
  __shared__ int lastf;
  int c = blockIdx.x, t = threadIdx.x;
  int idx = (int)(amax[c] & 0xffffffffULL);
  for (int i = t; i < 1024; i += 256) es[i] = eps[((size_t)c * S_ + idx) * R_ + i];
  __syncthreads();
  for (int rep = 0; rep < 4; rep++) {
    int i = rep * 256 + t;
    int q = i >> 7;
    float acc = 0.f;
    for (int pp = 0; pp < q; pp++) {
      const float* xr = (pp == 0) ? (sig + (size_t)i * 1024)
                                  : (XB + (size_t)(pp - 1) * 114688 + (size_t)(i - 128 * (pp + 1)) * 128);
      const float* ev = es + 128 * pp;
#pragma unroll 4
      for (int j = 0; j < 128; j++) acc += xr[j] * ev[j];
    }
    const float* dr = sig + (size_t)i * 1024;
    for (int j = 128 * q; j <= i; j++) acc += dr[j] * es[j];
    ys[i] = mu[c * R_ + i] * 1e-3f + acc;
  }
  __syncthreads();
  if (t < C_) {
    float acc = bp[t];
    const float* Wr = Wp + (size_t)t * R_;
    for (int j = 0; j < 1024; j++) acc += ys[j] * Wr[j];
    sv[t] = acc;
  }
  __syncthreads();
  if (t == 0) {
    float m = -1e30f;
    for (int k = 0; k < C_; k++) m = fmaxf(m, sv[k]);
    float sum = 0.f;
    for (int k = 0; k < C_; k++) sum += expf(sv[k] - m) * fmaxf(we[k], 0.f);
    E[N_ + c] = m + logf(sum);
    __threadfence();
    int d = atomicAdd(&cnt[9], 1);
    lastf = (d == C_ - 1) ? 1 : 0;
  }
  __syncthreads();
  if (!lastf) return;
  __threadfence();
  // ---- dist tail (one block) ----
  float* sW1 = darena;
  float* sb1 = darena + 512;
  float* sW2 = darena + 1024;
  float* red = darena + 1536;
  for (int i = t; i < 512; i += 256) { sW1[i] = W1[i]; sb1[i] = b1[i]; sW2[i] = W2[i]; }
  __syncthreads();
  float sum = 0.f;
  for (int i = t; i < N_ + C_; i += 256) {
    float e = E[i];
    float acc = b2[0];
    for (int j = 0; j < 512; j++) acc += sW2[j] * fmaxf(e * sW1[j] + sb1[j], 0.f);
    float y = (i < N_) ? 1.f : 0.f;
    float l = fmaxf(acc, 0.f) - acc * y + log1pf(expf(-fabsf(acc)));
    sum += l;
  }
#pragma unroll
  for (int d = 32; d > 0; d >>= 1) sum += __shfl_xor(sum, d);
  if ((t & 63) == 0) red[t >> 6] = sum;
  __syncthreads();
  if (t == 0) {
    out[1] = 0.1f * (red[0] + red[1] + red[2] + red[3]) / 522.f;
    out[0] = *cls_accum / 512.f;
  }
}

extern "C" void kernel_launch(void* const* d_in, const int* in_sizes, int n_in,
                              void* d_out, int out_size, void* d_ws, size_t ws_size,
                              hipStream_t stream) {
  (void)in_sizes; (void)n_in; (void)out_size; (void)ws_size;
  const float* box  = (const float*)d_in[0];
  const int*   lab  = (const int*)d_in[1];
  const float* idd  = (const float*)d_in[2];
  const float* Wp   = (const float*)d_in[4];
  const float* bp   = (const float*)d_in[5];
  const float* we   = (const float*)d_in[6];
  const float* W1   = (const float*)d_in[7];
  const float* b1   = (const float*)d_in[8];
  const float* W2   = (const float*)d_in[9];
  const float* b2   = (const float*)d_in[10];
  const float* eps  = (const float*)d_in[11];
  float* out = (float*)d_out;

  char* ws = (char*)d_ws;
  uint16_t* Dt = (uint16_t*)(ws + OFF_DT);
  float* GP    = (float*)(ws + OFF_GP);
  float* sig   = (float*)(ws + OFF_SIG);
  float* mu    = (float*)(ws + OFF_MU);
  float* E     = (float*)(ws + OFF_E);
  float* clsa  = (float*)(ws + OFF_CLS);
  unsigned long long* amax = (unsigned long long*)(ws + OFF_AMAX);
  int* cnt  = (int*)(ws + OFF_CNT);

  // zero mu/E/cls/amax/counters (counters must re-zero every graph iteration)
  hipMemsetAsync(ws + OFF_MU, 0, ZERO_BYTES, stream);
  // front: epsmax [0,1270) + scores [1270,1398) + convert [1398,3958)
  hipLaunchKernelGGL(k_front, dim3(3958), dim3(256), 0, stream,
                     box, lab, idd, Wp, bp, we, eps, Dt, mu, E, clsa, amax);
  hipLaunchKernelGGL(k_gemm, dim3(8, 8, SPLITK), dim3(256), 0, stream,
                     Dt, GP, mu, sig, cnt);
  for (int p = 0; p < 7; p++) {
    int nb = 14 - 2 * p;
    int nt = nb * (nb + 1) / 2;
    hipLaunchKernelGGL(k_tsyrk, dim3(nt), dim3(256), 0, stream,
                       sig, GP, mu, cnt, p, nt);
  }
  hipLaunchKernelGGL(k_vosdist, dim3(C_), dim3(256), 0, stream,
                     eps, sig, GP, mu, Wp, bp, we, amax, E,
                     W1, b1, W2, b2, clsa, out, cnt);
}